// Round 8
// baseline (146.777 us; speedup 1.0000x reference)
//
#include <hip/hip_runtime.h>
#include <hip/hip_bf16.h>
#include <hip/hip_fp16.h>

typedef _Float16 half8 __attribute__((ext_vector_type(8)));
typedef _Float16 half4 __attribute__((ext_vector_type(4)));
typedef float    floatx4 __attribute__((ext_vector_type(4)));

#define BM 64

// ---------------------------------------------------------------------------
// Kernel 1: W in MFMA-fragment order. Element index:
//   idx = ((((l*4 + wc)*8 + s)*4 + nf)*64 + lane), value block = 8 halves (16 B)
//   content: W^T[n][k] * scale with n = wc*64+nf*16+(lane&15),
//            k = s*32 + (lane>>4)*8 + j
// so a wave's B-fragment load is contiguous: base + lane*16.
// ---------------------------------------------------------------------------
__global__ void make_weights_frag(const float* __restrict__ p0, const float* __restrict__ p1,
                                  const float* __restrict__ p2, const float* __restrict__ p3,
                                  _Float16* __restrict__ wt) {
    int idx  = blockIdx.x * blockDim.x + threadIdx.x;   // 0 .. 24575
    int lane = idx & 63;
    int nf   = (idx >> 6) & 3;
    int s    = (idx >> 8) & 7;
    int wc   = (idx >> 11) & 3;
    int l    = idx >> 13;
    int n  = wc * 64 + nf * 16 + (lane & 15);
    int k0 = s * 32 + (lane >> 4) * 8;
    const float* P[4] = {p0, p1, p2, p3};
    const float* pb = P[l + 1] + n * 20;
    float pbr[20];
    #pragma unroll
    for (int i = 0; i < 20; ++i) pbr[i] = pb[i];
    half8 o;
    #pragma unroll
    for (int j = 0; j < 8; ++j) {
        const float* pa = P[l] + (k0 + j) * 20;
        float d2 = 0.f;
        #pragma unroll
        for (int i = 0; i < 20; ++i) { float df = pa[i] - pbr[i]; d2 += df * df; }
        float d = sqrtf(d2);
        float m = fmodf(d, 0.2f);                            // == np.mod, d >= 0
        o[j] = (_Float16)(10.0f * (0.05f - fabsf(m - 0.1f)) * 0.0625f);
    }
    *reinterpret_cast<half8*>(wt + (size_t)idx * 8) = o;
}

// ---------------------------------------------------------------------------
// Kernel 2: fused 3-layer forward, W-dedup layout.
//   - Block = 64 rows x 256 cols, 256 threads, 4 waves; wave w = col tile
//     wc=w (64x64 output tile, acc[4][4] -> AGPRs). Each wave reads a
//     DISTINCT W[l][wc] slice -> zero intra-block W redundancy: block W
//     traffic = 384 KB (min), half of the 8-wave version. L2 queueing drops.
//   - z in single 32 KB XOR-swizzled LDS buffer, in-place layer update,
//     5 barriers/block (x-stage, 2 per inner layer boundary).
//   - W register double-buffered one K-step ahead + next-segment step-0
//     prefetch before each barrier (R4-proven schedule).
//   - 4 blocks/CU co-resident (LDS 4x32 KB, regs: 64 acc AGPR + ~60 VGPR).
// ---------------------------------------------------------------------------
__global__ __launch_bounds__(256, 4) void pcn_fused(
    const float* __restrict__ x, const _Float16* __restrict__ wt,
    const float* __restrict__ b1, const float* __restrict__ b2,
    const float* __restrict__ b3, float* __restrict__ out) {

    // z[row][k]: byte = row*512 + ((k/8)^(row&7))*16 + (k&7)*2
    __shared__ __align__(16) _Float16 zlds[BM * 256];   // 32,768 B

    const int t    = threadIdx.x;
    const int lane = t & 63;
    const int wc   = t >> 6;      // 0..3  (64-col tile; all 64 rows)
    const int l15  = lane & 15;
    const int lg   = lane >> 4;   // 0..3
    const size_t row0 = (size_t)blockIdx.x * BM;

    char* const zb = reinterpret_cast<char*>(zlds);

    half8   bb[2][4];
    floatx4 acc[4][4];

    // ---- stage x: 64x256 f32 -> fp16 swizzled. 16 float4/thread in 4 batches.
    #pragma unroll
    for (int b = 0; b < 4; ++b) {
        floatx4 xr[4];
        #pragma unroll
        for (int i = 0; i < 4; ++i) {
            int g   = (b * 4 + i) * 256 + t;   // float4 index in [64][64]
            int row = g >> 6, c4 = g & 63;
            xr[i] = *reinterpret_cast<const floatx4*>(x + (row0 + row) * 256 + c4 * 4);
        }
        #pragma unroll
        for (int i = 0; i < 4; ++i) {
            int g   = (b * 4 + i) * 256 + t;
            int row = g >> 6, c4 = g & 63;
            half4 h;
            h[0] = (_Float16)xr[i][0]; h[1] = (_Float16)xr[i][1];
            h[2] = (_Float16)xr[i][2]; h[3] = (_Float16)xr[i][3];
            int chunk = (c4 >> 1) ^ (row & 7);
            *reinterpret_cast<half4*>(zb + row * 512 + chunk * 16 + (c4 & 1) * 8) = h;
        }
    }
    // prefetch layer-0 step-0 W fragments (contiguous 1 KB per load)
    {
        const _Float16* w0 = wt + ((size_t)wc << 14);
        #pragma unroll
        for (int nf = 0; nf < 4; ++nf)
            bb[0][nf] = *reinterpret_cast<const half8*>(w0 + nf * 512 + lane * 8);
    }
    __syncthreads();

    #pragma unroll
    for (int l = 0; l < 3; ++l) {
        const float* bias = (l == 0) ? b1 : (l == 1) ? b2 : b3;
        const _Float16* wlp = wt + (((size_t)l * 4 + wc) << 14);

        // bias -> accumulator init (broadcast along rows)
        #pragma unroll
        for (int nf = 0; nf < 4; ++nf) {
            const float bv = bias[wc * 64 + nf * 16 + l15];
            #pragma unroll
            for (int mf = 0; mf < 4; ++mf)
                acc[mf][nf] = floatx4{bv, bv, bv, bv};
        }

        #pragma unroll
        for (int s = 0; s < 8; ++s) {            // K-step of 32
            if (s < 7) {
                #pragma unroll
                for (int nf = 0; nf < 4; ++nf)
                    bb[(s + 1) & 1][nf] = *reinterpret_cast<const half8*>(
                        wlp + (s + 1) * 2048 + nf * 512 + lane * 8);
            }
            const int vchunk = (s * 4 + lg) ^ (l15 & 7);
            half8 a[4];
            #pragma unroll
            for (int mf = 0; mf < 4; ++mf)
                a[mf] = *reinterpret_cast<const half8*>(
                    zb + (mf * 16 + l15) * 512 + vchunk * 16);
            #pragma unroll
            for (int mf = 0; mf < 4; ++mf)
                #pragma unroll
                for (int nf = 0; nf < 4; ++nf)
                    acc[mf][nf] = __builtin_amdgcn_mfma_f32_16x16x32_f16(
                        a[mf], bb[s & 1][nf], acc[mf][nf], 0, 0, 0);
        }

        // prefetch next segment's step-0 W (next layer; dead for l==2 tail)
        if (l < 2) {
            const _Float16* wn = wt + (((size_t)(l + 1) * 4 + wc) << 14);
            #pragma unroll
            for (int nf = 0; nf < 4; ++nf)
                bb[0][nf] = *reinterpret_cast<const half8*>(wn + nf * 512 + lane * 8);
        }

        if (l < 2) {
            __syncthreads();   // all waves done READING zlds
            // relu + cvt -> zlds in place (bias already in acc)
            #pragma unroll
            for (int nf = 0; nf < 4; ++nf) {
                const int n = wc * 64 + nf * 16 + l15;
                #pragma unroll
                for (int mf = 0; mf < 4; ++mf) {
                    const int mrow = mf * 16 + lg * 4;
                    #pragma unroll
                    for (int r = 0; r < 4; ++r) {
                        float v = fmaxf(acc[mf][nf][r], 0.0f);
                        const int row  = mrow + r;
                        const int byte = row * 512 + (((n >> 3) ^ (row & 7)) << 4)
                                       + (n & 7) * 2;
                        *reinterpret_cast<_Float16*>(zb + byte) = (_Float16)v;
                    }
                }
            }
            __syncthreads();   // writes visible before next layer's reads
        } else {
            // final layer: f32 out (bias already in acc); block exits after
            #pragma unroll
            for (int nf = 0; nf < 4; ++nf) {
                const int n = wc * 64 + nf * 16 + l15;
                #pragma unroll
                for (int mf = 0; mf < 4; ++mf) {
                    const size_t mrow = row0 + mf * 16 + lg * 4;
                    #pragma unroll
                    for (int r = 0; r < 4; ++r)
                        out[(mrow + r) * 256 + n] = acc[mf][nf][r];
                }
            }
        }
    }
}

extern "C" void kernel_launch(void* const* d_in, const int* in_sizes, int n_in,
                              void* d_out, int out_size, void* d_ws, size_t ws_size,
                              hipStream_t stream) {
    const float* x  = (const float*)d_in[0];
    const float* p0 = (const float*)d_in[1];
    const float* p1 = (const float*)d_in[2];
    const float* p2 = (const float*)d_in[3];
    const float* p3 = (const float*)d_in[4];
    const float* b1 = (const float*)d_in[5];
    const float* b2 = (const float*)d_in[6];
    const float* b3 = (const float*)d_in[7];
    float* out = (float*)d_out;
    _Float16* wt = (_Float16*)d_ws;              // 3*4*8*4*64*8 halves = 384 KB

    const int B = in_sizes[0] / 256;             // 131072

    make_weights_frag<<<96, 256, 0, stream>>>(p0, p1, p2, p3, wt);
    pcn_fused<<<B / BM, 256, 0, stream>>>(x, wt, b1, b2, b3, out);
}

// Round 9
// 84.671 us; speedup vs baseline: 1.7335x; 1.7335x over previous
//
#include <hip/hip_runtime.h>
#include <hip/hip_bf16.h>
#include <hip/hip_fp16.h>

typedef _Float16 half8 __attribute__((ext_vector_type(8)));
typedef _Float16 half4 __attribute__((ext_vector_type(4)));
typedef float    floatx4 __attribute__((ext_vector_type(4)));

#define BM 64

// ---------------------------------------------------------------------------
// Kernel 1: W in MFMA-fragment order. Element index:
//   idx = ((((l*4 + wc)*8 + s)*4 + nf)*64 + lane), value block = 8 halves (16 B)
//   content: W^T[n][k] * scale with n = wc*64+nf*16+(lane&15),
//            k = s*32 + (lane>>4)*8 + j
// A wave's B-fragment load is contiguous: base + lane*16.
// ---------------------------------------------------------------------------
__global__ void make_weights_frag(const float* __restrict__ p0, const float* __restrict__ p1,
                                  const float* __restrict__ p2, const float* __restrict__ p3,
                                  _Float16* __restrict__ wt) {
    int idx  = blockIdx.x * blockDim.x + threadIdx.x;   // 0 .. 24575
    int lane = idx & 63;
    int nf   = (idx >> 6) & 3;
    int s    = (idx >> 8) & 7;
    int wc   = (idx >> 11) & 3;
    int l    = idx >> 13;
    int n  = wc * 64 + nf * 16 + (lane & 15);
    int k0 = s * 32 + (lane >> 4) * 8;
    const float* P[4] = {p0, p1, p2, p3};
    const float* pb = P[l + 1] + n * 20;
    float pbr[20];
    #pragma unroll
    for (int i = 0; i < 20; ++i) pbr[i] = pb[i];
    half8 o;
    #pragma unroll
    for (int j = 0; j < 8; ++j) {
        const float* pa = P[l] + (k0 + j) * 20;
        float d2 = 0.f;
        #pragma unroll
        for (int i = 0; i < 20; ++i) { float df = pa[i] - pbr[i]; d2 += df * df; }
        float d = sqrtf(d2);
        float m = fmodf(d, 0.2f);                            // == np.mod, d >= 0
        o[j] = (_Float16)(10.0f * (0.05f - fabsf(m - 0.1f)) * 0.0625f);
    }
    *reinterpret_cast<half8*>(wt + (size_t)idx * 8) = o;
}

// ---------------------------------------------------------------------------
// Kernel 2: fused 3-layer forward — R7 shell, W-dedup wave mapping.
//   - Block = 64 rows x 256 cols, 512 threads, 8 waves. Wave wv owns ALL 64
//     rows x cols [wv*32, wv*32+32): acc[4][2] = 32 regs; every wave reads a
//     DISTINCT W column slice -> block W traffic = 384 KB (minimum), half of
//     R7; W-load instructions per step: 2 (was 4).
//   - z ping-pongs between two 32 KB XOR-swizzled LDS buffers (compile-time
//     pointers): l0 rd buf0 wr buf1; l1 rd buf1 wr buf0; l2 rd buf0 -> out.
//     3 __syncthreads per block.
//   - W register ring-buffer TWO K-steps ahead (bb[3][2], static indices in
//     the fully unrolled 24-step body). Steady register demand ~95 < 128.
// ---------------------------------------------------------------------------
__global__ __launch_bounds__(512, 4) void pcn_fused(
    const float* __restrict__ x, const _Float16* __restrict__ wt,
    const float* __restrict__ b1, const float* __restrict__ b2,
    const float* __restrict__ b3, float* __restrict__ out) {

    // z[row][k] in buf b: byte = b*32768 + row*512 + ((k/8)^(row&7))*16 + (k&7)*2
    __shared__ __align__(16) _Float16 zlds[2][BM * 256];   // 65,536 B

    const int t    = threadIdx.x;
    const int lane = t & 63;
    const int wv   = t >> 6;      // 0..7: column slice [wv*32, wv*32+32)
    const int l15  = lane & 15;
    const int lg   = lane >> 4;   // 0..3
    const size_t row0 = (size_t)blockIdx.x * BM;

    char* const zb0 = reinterpret_cast<char*>(&zlds[0][0]);
    char* const zb1 = reinterpret_cast<char*>(&zlds[1][0]);

    half8   bb[3][2];             // ring: step g uses bb[g%3]
    floatx4 acc[4][2];

    // W fragment address for global step g (= l*8+s), col sub-frag j (0..1):
    // old-layout coords: wc = wv>>1, nf = (wv&1)*2 + j.
    auto wfrag = [&](int g, int j) -> const half8* {
        const int gl = g >> 3, gs = g & 7;
        return reinterpret_cast<const half8*>(
            wt + (((size_t)gl * 4 + (wv >> 1)) << 14) + gs * 2048
               + ((wv & 1) * 2 + j) * 512 + lane * 8);
    };

    // ---- stage x: 64x256 f32 -> fp16 swizzled into buf0. 8 float4/thread.
    {
        floatx4 xr[8];
        #pragma unroll
        for (int i = 0; i < 8; ++i) {
            int g   = i * 512 + t;        // float4 index in [64][64]
            int row = g >> 6, c4 = g & 63;
            xr[i] = *reinterpret_cast<const floatx4*>(x + (row0 + row) * 256 + c4 * 4);
        }
        #pragma unroll
        for (int i = 0; i < 8; ++i) {
            int g   = i * 512 + t;
            int row = g >> 6, c4 = g & 63;
            half4 h;
            h[0] = (_Float16)xr[i][0]; h[1] = (_Float16)xr[i][1];
            h[2] = (_Float16)xr[i][2]; h[3] = (_Float16)xr[i][3];
            int chunk = (c4 >> 1) ^ (row & 7);
            *reinterpret_cast<half4*>(zb0 + row * 512 + chunk * 16 + (c4 & 1) * 8) = h;
        }
    }
    // prefetch W steps g=0,1 while x-writes drain
    #pragma unroll
    for (int j = 0; j < 2; ++j) bb[0][j] = *wfrag(0, j);
    #pragma unroll
    for (int j = 0; j < 2; ++j) bb[1][j] = *wfrag(1, j);
    __syncthreads();

    #pragma unroll
    for (int l = 0; l < 3; ++l) {
        const float* bias = (l == 0) ? b1 : (l == 1) ? b2 : b3;
        char* const rz = (l == 1) ? zb1 : zb0;     // layer input buffer

        // bias -> accumulator init (broadcast along rows)
        #pragma unroll
        for (int j = 0; j < 2; ++j) {
            const float bv = bias[wv * 32 + j * 16 + l15];
            #pragma unroll
            for (int mf = 0; mf < 4; ++mf)
                acc[mf][j] = floatx4{bv, bv, bv, bv};
        }

        #pragma unroll
        for (int s = 0; s < 8; ++s) {            // K-step of 32; global step g
            const int g = l * 8 + s;
            if (g + 2 < 24) {
                #pragma unroll
                for (int j = 0; j < 2; ++j)
                    bb[(g + 2) % 3][j] = *wfrag(g + 2, j);
            }
            const int vchunk = (s * 4 + lg) ^ (l15 & 7);
            half8 a[4];
            #pragma unroll
            for (int mf = 0; mf < 4; ++mf)
                a[mf] = *reinterpret_cast<const half8*>(
                    rz + (mf * 16 + l15) * 512 + vchunk * 16);
            #pragma unroll
            for (int mf = 0; mf < 4; ++mf)
                #pragma unroll
                for (int j = 0; j < 2; ++j)
                    acc[mf][j] = __builtin_amdgcn_mfma_f32_16x16x32_f16(
                        a[mf], bb[g % 3][j], acc[mf][j], 0, 0, 0);
        }

        if (l < 2) {
            // relu + cvt -> the OTHER buffer (not read by anyone this phase)
            char* const wz = (l == 0) ? zb1 : zb0;
            #pragma unroll
            for (int j = 0; j < 2; ++j) {
                const int n = wv * 32 + j * 16 + l15;
                #pragma unroll
                for (int mf = 0; mf < 4; ++mf) {
                    const int mrow = mf * 16 + lg * 4;
                    #pragma unroll
                    for (int r = 0; r < 4; ++r) {
                        float v = fmaxf(acc[mf][j][r], 0.0f);
                        const int row  = mrow + r;
                        const int byte = row * 512 + (((n >> 3) ^ (row & 7)) << 4)
                                       + (n & 7) * 2;
                        *reinterpret_cast<_Float16*>(wz + byte) = (_Float16)v;
                    }
                }
            }
            __syncthreads();
        } else {
            // final layer: f32 out (bias already in acc); block exits after
            #pragma unroll
            for (int j = 0; j < 2; ++j) {
                const int n = wv * 32 + j * 16 + l15;
                #pragma unroll
                for (int mf = 0; mf < 4; ++mf) {
                    const size_t mrow = row0 + mf * 16 + lg * 4;
                    #pragma unroll
                    for (int r = 0; r < 4; ++r)
                        out[(mrow + r) * 256 + n] = acc[mf][j][r];
                }
            }
        }
    }
}

extern "C" void kernel_launch(void* const* d_in, const int* in_sizes, int n_in,
                              void* d_out, int out_size, void* d_ws, size_t ws_size,
                              hipStream_t stream) {
    const float* x  = (const float*)d_in[0];
    const float* p0 = (const float*)d_in[1];
    const float* p1 = (const float*)d_in[2];
    const float* p2 = (const float*)d_in[3];
    const float* p3 = (const float*)d_in[4];
    const float* b1 = (const float*)d_in[5];
    const float* b2 = (const float*)d_in[6];
    const float* b3 = (const float*)d_in[7];
    float* out = (float*)d_out;
    _Float16* wt = (_Float16*)d_ws;              // 3*4*8*4*64*8 halves = 384 KB

    const int B = in_sizes[0] / 256;             // 131072

    make_weights_frag<<<96, 256, 0, stream>>>(p0, p1, p2, p3, wt);
    pcn_fused<<<B / BM, 512, 0, stream>>>(x, wt, b1, b2, b3, out);
}